// Round 12
// baseline (198.035 us; speedup 1.0000x reference)
//
#include <hip/hip_runtime.h>
#include <stdint.h>

// Workspace byte offsets
#define OFF_W1  0        // 1024*32 u32 packed sign bits (784 bits + zero pad)
#define OFF_W2  131072
#define OFF_W3  262144
#define OFF_WFC 393216   // 10*32 u32
#define OFF_T1  395264   // 1024 int32 popcount thresholds
#define OFF_T2  399360
#define OFF_T3  403456
#define OFF_SFC 407552   // double: mean|wfc|
#define OFF_P   409600   // 1 MB bit buffer (ping): packed x, then act2
#define OFF_Q   1458176  // 1 MB bit buffer (pong): act1, then act3
#define WS_NEED_SPLIT 2506752u
#define RWS 8            // rows/block in fallback fused kernel

typedef uint32_t u32x16 __attribute__((ext_vector_type(16)));

// ---------------------------------------------------------------------------
// Prep (R10/R11, works): one dispatch = W-pack + thresholds + wfc + x-pack.
//   blocks 0..383   : thread = (layer, channel o, word k); packs 32 weights
//                     into one u32 (bit=1 <=> w>=0, sign(0)=+1); per-channel
//                     mean|w| via half-wave shfl_xor tree. Threshold (double,
//                     exact): dot = K-2p; layer+BN+sign == (p <= Tint[o]).
//   block 384       : wfc pack (320 words) + global mean|wfc| block-reduce.
//   blocks 385..1408: x-pack, thread = one u32 word; bit j of word w =
//                     (x[r][32w+j] >= 0.5); words 25..31 = 0 (match W1 pad).
// ---------------------------------------------------------------------------
__global__ __launch_bounds__(256) void bnn_prep(
    const float* __restrict__ x,
    const float* __restrict__ w1, const float* __restrict__ b1, const float* __restrict__ g1,
    const float* __restrict__ be1, const float* __restrict__ m1, const float* __restrict__ v1,
    const float* __restrict__ w2, const float* __restrict__ b2, const float* __restrict__ g2,
    const float* __restrict__ be2, const float* __restrict__ m2, const float* __restrict__ v2,
    const float* __restrict__ w3, const float* __restrict__ b3, const float* __restrict__ g3,
    const float* __restrict__ be3, const float* __restrict__ m3, const float* __restrict__ v3,
    const float* __restrict__ wfc,
    uint32_t* __restrict__ ws)
{
    const int blk  = blockIdx.x;
    const int t    = threadIdx.x;
    const int lane = t & 63;
    const int wv   = t >> 6;

    if (blk < 384) {
        const int gid = blk * 256 + t;      // 0..98303
        const int l   = gid >> 15;          // layer 0..2 (32768 words each)
        const int rem = gid & 32767;
        const int o   = rem >> 5;           // channel
        const int k   = rem & 31;           // word within channel
        const float *w, *bb, *g, *be, *m, *v;
        int K; uint32_t* Wp; int* T;
        if (l == 0)      { w=w1; bb=b1; g=g1; be=be1; m=m1; v=v1; K=784;  Wp = ws + OFF_W1/4; T = (int*)(ws + OFF_T1/4); }
        else if (l == 1) { w=w2; bb=b2; g=g2; be=be2; m=m2; v=v2; K=1024; Wp = ws + OFF_W2/4; T = (int*)(ws + OFF_T2/4); }
        else             { w=w3; bb=b3; g=g3; be=be3; m=m3; v=v3; K=1024; Wp = ws + OFF_W3/4; T = (int*)(ws + OFF_T3/4); }

        const int base = 32 * k;
        uint32_t bits = 0;
        double s = 0.0;
        if (base < K) {
            const float4* p = (const float4*)(w + (size_t)o * K + base);
            const int n4 = (K - base >= 32) ? 8 : 4;   // K=784, k=24 -> 16 elems
            for (int i = 0; i < n4; ++i) {
                float4 q = p[i];
                bits |= (q.x >= 0.0f) ? (1u << (4*i + 0)) : 0u;
                bits |= (q.y >= 0.0f) ? (1u << (4*i + 1)) : 0u;
                bits |= (q.z >= 0.0f) ? (1u << (4*i + 2)) : 0u;
                bits |= (q.w >= 0.0f) ? (1u << (4*i + 3)) : 0u;
                s += fabs((double)q.x) + fabs((double)q.y)
                   + fabs((double)q.z) + fabs((double)q.w);
            }
        }
        // half-wave (32-lane) xor tree: all lanes of the half get channel sum
        #pragma unroll
        for (int mask = 1; mask <= 16; mask <<= 1)
            s += __shfl_xor(s, mask, 64);
        if (k == 0) {
            double scale = s / (double)K;                        // mean|w| > 0
            double r = (double)g[o] / sqrt((double)v[o] + 1e-5); // > 0
            double tt = (((double)m[o] - (double)bb[o]) * r - (double)be[o]) / (scale * r);
            double C  = ceil(tt);                                // dot >= C
            double Td = floor(((double)K - C) * 0.5);            // p <= Td
            Td = fmax(fmin(Td, 100000.0), -1.0);
            T[o] = (int)Td;
        }
        Wp[(size_t)o * 32 + k] = bits;
    } else if (blk == 384) {
        // wfc: 320 words (10 ch x 32); thread t does word t and (t<64) t+256
        uint32_t* Wp = ws + OFF_WFC/4;
        double s = 0.0;
        {
            const int o = t >> 5, k = t & 31;
            const float4* p = (const float4*)(wfc + o * 1024 + 32 * k);
            uint32_t bits = 0;
            #pragma unroll
            for (int i = 0; i < 8; ++i) {
                float4 q = p[i];
                bits |= (q.x >= 0.0f) ? (1u << (4*i + 0)) : 0u;
                bits |= (q.y >= 0.0f) ? (1u << (4*i + 1)) : 0u;
                bits |= (q.z >= 0.0f) ? (1u << (4*i + 2)) : 0u;
                bits |= (q.w >= 0.0f) ? (1u << (4*i + 3)) : 0u;
                s += fabs((double)q.x) + fabs((double)q.y)
                   + fabs((double)q.z) + fabs((double)q.w);
            }
            Wp[t] = bits;
        }
        if (t < 64) {
            const int t2 = t + 256;
            const int o = t2 >> 5, k = t2 & 31;
            const float4* p = (const float4*)(wfc + o * 1024 + 32 * k);
            uint32_t bits = 0;
            #pragma unroll
            for (int i = 0; i < 8; ++i) {
                float4 q = p[i];
                bits |= (q.x >= 0.0f) ? (1u << (4*i + 0)) : 0u;
                bits |= (q.y >= 0.0f) ? (1u << (4*i + 1)) : 0u;
                bits |= (q.z >= 0.0f) ? (1u << (4*i + 2)) : 0u;
                bits |= (q.w >= 0.0f) ? (1u << (4*i + 3)) : 0u;
                s += fabs((double)q.x) + fabs((double)q.y)
                   + fabs((double)q.z) + fabs((double)q.w);
            }
            Wp[t2] = bits;
        }
        __shared__ double red[4];
        #pragma unroll
        for (int off = 32; off > 0; off >>= 1) s += __shfl_down(s, off, 64);
        if (lane == 0) red[wv] = s;
        __syncthreads();
        if (t == 0)
            *(double*)(ws + OFF_SFC/4) = (red[0] + red[1] + red[2] + red[3]) / 10240.0;
    } else {
        // x-pack (split path only): gid = one u32 word
        const int gid = (blk - 385) * 256 + t;   // 0..262143
        const int r = gid >> 5;
        const int w = gid & 31;
        uint32_t bits = 0;
        if (w < 24) {
            const float4* p = (const float4*)(x + (size_t)r * 784 + 32 * w);
            #pragma unroll
            for (int i = 0; i < 8; ++i) {
                float4 q = p[i];
                bits |= (q.x >= 0.5f) ? (1u << (4*i + 0)) : 0u;
                bits |= (q.y >= 0.5f) ? (1u << (4*i + 1)) : 0u;
                bits |= (q.z >= 0.5f) ? (1u << (4*i + 2)) : 0u;
                bits |= (q.w >= 0.5f) ? (1u << (4*i + 3)) : 0u;
            }
        } else if (w == 24) {
            const float4* p = (const float4*)(x + (size_t)r * 784 + 768);
            #pragma unroll
            for (int i = 0; i < 4; ++i) {
                float4 q = p[i];
                bits |= (q.x >= 0.5f) ? (1u << (4*i + 0)) : 0u;
                bits |= (q.y >= 0.5f) ? (1u << (4*i + 1)) : 0u;
                bits |= (q.z >= 0.5f) ? (1u << (4*i + 2)) : 0u;
                bits |= (q.w >= 0.5f) ? (1u << (4*i + 3)) : 0u;
            }
        }
        (ws + OFF_P/4)[gid] = bits;
    }
}

// ---------------------------------------------------------------------------
// Layer kernel, lane = batch row. BOTH operands remat-proof:
//   A: inline-asm global_load_dwordx4 x8 + vmcnt(0) -> the 32 activation
//      dwords are asm-produced values, which the allocator CANNOT
//      rematerialize (R8 evidence of the disease: VGPR_Count=36 < |A[32]|
//      + misc, i.e. A was re-loaded from global per channel group -> 2KB/lane
//      redundant L1 traffic -> layers 3x the 6.8us VALU floor).
//   W: inline-asm s_load_dwordx16 channel pairs through the scalar pipe.
// VGPR budget: 32(A)+~12 misc ≈ 48 < 64-cap of a 1024-thr block at 8
// waves/SIMD -> no occupancy fight. Grid 512 = 128 rg x 4 cg, 2 blk/CU.
// Wave = 16 channels: slice = cg*16+wv; output u16 at act16[row*64+slice]
// (little-endian: u16 pair == u32 word for next layer's reads).
// ---------------------------------------------------------------------------
__global__ __launch_bounds__(1024) void bnn_layer(
    const uint32_t* __restrict__ actIn,
    const uint32_t* __restrict__ W,
    const int* __restrict__ T,
    uint32_t* __restrict__ actOut)
{
    const int t    = threadIdx.x;
    const int lane = t & 63;
    const int wv   = t >> 6;            // 0..15
    const int rg   = blockIdx.x >> 2;   // 0..127
    const int cg   = blockIdx.x & 3;    // 0..3
    const int row  = rg * 64 + lane;

    // A row via asm loads -> guaranteed register-resident across channel loop
    uint4 a0, a1, a2, a3, a4, a5, a6, a7;
    {
        const uint32_t* ap = actIn + (size_t)row * 32;
        asm volatile(
            "global_load_dwordx4 %0, %8, off\n\t"
            "global_load_dwordx4 %1, %8, off offset:16\n\t"
            "global_load_dwordx4 %2, %8, off offset:32\n\t"
            "global_load_dwordx4 %3, %8, off offset:48\n\t"
            "global_load_dwordx4 %4, %8, off offset:64\n\t"
            "global_load_dwordx4 %5, %8, off offset:80\n\t"
            "global_load_dwordx4 %6, %8, off offset:96\n\t"
            "global_load_dwordx4 %7, %8, off offset:112\n\t"
            "s_waitcnt vmcnt(0)"
            : "=v"(a0), "=v"(a1), "=v"(a2), "=v"(a3),
              "=v"(a4), "=v"(a5), "=v"(a6), "=v"(a7)
            : "v"(ap));
    }
    uint32_t A[32];
    *(uint4*)&A[0]  = a0;  *(uint4*)&A[4]  = a1;
    *(uint4*)&A[8]  = a2;  *(uint4*)&A[12] = a3;
    *(uint4*)&A[16] = a4;  *(uint4*)&A[20] = a5;
    *(uint4*)&A[24] = a6;  *(uint4*)&A[28] = a7;

    const int slice = __builtin_amdgcn_readfirstlane(cg * 16 + wv);   // 0..63
    const int* tp = T + slice * 16;     // uniform -> compiler scalarizes

    uint32_t outw = 0;
    #pragma unroll
    for (int c = 0; c < 16; c += 2) {
        const uint32_t* wp = W + (((size_t)slice * 16 + c) << 5);
        u32x16 w0lo, w0hi, w1lo, w1hi;
        asm volatile("s_load_dwordx16 %0, %4, 0x0\n\t"
                     "s_load_dwordx16 %1, %4, 0x40\n\t"
                     "s_load_dwordx16 %2, %4, 0x80\n\t"
                     "s_load_dwordx16 %3, %4, 0xc0\n\t"
                     "s_waitcnt lgkmcnt(0)"
                     : "=s"(w0lo), "=s"(w0hi), "=s"(w1lo), "=s"(w1hi)
                     : "s"(wp));
        int pa = 0, pb = 0, pc = 0, pd = 0;   // 4 chains (2 per channel)
        #pragma unroll
        for (int i = 0; i < 16; ++i) {
            pa += __popc(A[i]      ^ w0lo[i]);
            pb += __popc(A[i + 16] ^ w0hi[i]);
            pc += __popc(A[i]      ^ w1lo[i]);
            pd += __popc(A[i + 16] ^ w1hi[i]);
        }
        outw |= ((pa + pb) <= tp[c])     ? (1u << c)       : 0u;
        outw |= ((pc + pd) <= tp[c + 1]) ? (1u << (c + 1)) : 0u;
    }
    ((uint16_t*)actOut)[(size_t)row * 64 + slice] = (uint16_t)outw;
}

// FC: lane = row; 10 channels. out = (1024-2p)*sfc + bfc[c] (exact int dot).
__global__ __launch_bounds__(64) void bnn_fc(
    const uint32_t* __restrict__ act3,
    const uint32_t* __restrict__ ws,
    const float* __restrict__ bfc,
    float* __restrict__ out)
{
    const int lane = threadIdx.x;
    const int row  = blockIdx.x * 64 + lane;

    uint32_t A[32];
    const uint4* ap = (const uint4*)(act3 + (size_t)row * 32);
    #pragma unroll
    for (int i = 0; i < 8; ++i) ((uint4*)A)[i] = ap[i];

    const float sfc = (float)(*(const double*)(ws + OFF_SFC/4));
    const uint32_t* Wfc = ws + OFF_WFC/4;
    #pragma unroll
    for (int ch = 0; ch < 10; ++ch) {
        const uint32_t* wp = Wfc + ch * 32;
        int p = 0;
        #pragma unroll
        for (int i = 0; i < 32; ++i) p += __popc(A[i] ^ wp[i]);
        out[(size_t)row * 10 + ch] = (float)(1024 - 2 * p) * sfc + bfc[ch];
    }
}

// ---------------------------------------------------------------------------
// FALLBACK fused kernel (R4, 89.5us; ws need 408 KB) — used if ws too small.
// ---------------------------------------------------------------------------
__global__ __launch_bounds__(512, 4) void bnn_fused(
    const float* __restrict__ x,
    const uint32_t* __restrict__ ws,
    const float* __restrict__ bfc,
    float* __restrict__ out)
{
    __shared__ alignas(16) uint32_t bufA[RWS][32];
    __shared__ alignas(16) uint32_t bufB[RWS][32];
    const int t    = threadIdx.x;
    const int lane = t & 63;
    const int wv   = t >> 6;
    const int row0 = blockIdx.x * RWS;

    {
        const float* xr = x + (size_t)(row0 + wv) * 784;
        #pragma unroll
        for (int k = 0; k < 13; ++k) {
            const int idx = k * 64 + lane;
            const bool bit = (idx < 784) && (xr[idx] >= 0.5f);
            unsigned long long m = __ballot(bit);
            if (lane == 0) *(uint64_t*)(&bufA[wv][2 * k]) = m;
        }
        if (lane == 0) {
            *(uint64_t*)(&bufA[wv][26]) = 0ull;
            *(uint64_t*)(&bufA[wv][28]) = 0ull;
            *(uint64_t*)(&bufA[wv][30]) = 0ull;
        }
    }
    __syncthreads();

    const uint32_t* Wbase[3] = { ws + OFF_W1/4, ws + OFF_W2/4, ws + OFF_W3/4 };
    const int*      Tbase[3] = { (const int*)(ws + OFF_T1/4), (const int*)(ws + OFF_T2/4), (const int*)(ws + OFF_T3/4) };

    uint32_t (*cur)[32] = bufA;
    uint32_t (*nxt)[32] = bufB;
    const int c0 = t, c1 = t + 512;

    for (int l = 0; l < 3; ++l) {
        uint32_t W0[32], W1[32];
        {
            const uint4* p0 = (const uint4*)(Wbase[l] + (size_t)c0 * 32);
            const uint4* p1 = (const uint4*)(Wbase[l] + (size_t)c1 * 32);
            #pragma unroll
            for (int i = 0; i < 8; ++i) { ((uint4*)W0)[i] = p0[i]; ((uint4*)W1)[i] = p1[i]; }
        }
        const int T0 = Tbase[l][c0];
        const int T1 = Tbase[l][c1];

        for (int r = 0; r < RWS; ++r) {
            uint32_t A[32];
            #pragma unroll
            for (int i = 0; i < 8; ++i) ((uint4*)A)[i] = ((const uint4*)cur[r])[i];
            int pa = 0, pb = 0, pc = 0, pd = 0;
            #pragma unroll
            for (int i = 0; i < 16; ++i) {
                pa += __popc(A[i]      ^ W0[i]);
                pb += __popc(A[i + 16] ^ W0[i + 16]);
                pc += __popc(A[i]      ^ W1[i]);
                pd += __popc(A[i + 16] ^ W1[i + 16]);
            }
            unsigned long long m0 = __ballot((pa + pb) <= T0);
            unsigned long long m1 = __ballot((pc + pd) <= T1);
            if (lane == 0) {
                *(uint64_t*)(&nxt[r][2 * wv])      = m0;
                *(uint64_t*)(&nxt[r][16 + 2 * wv]) = m1;
            }
        }
        __syncthreads();
        uint32_t (*tmp)[32] = cur; cur = nxt; nxt = tmp;
    }

    if (t < RWS * 10) {
        const float sfc = (float)(*(const double*)(ws + OFF_SFC/4));
        const uint32_t* Wfc = ws + OFF_WFC/4;
        const int r = t / 10, ch = t % 10;
        const uint32_t* wrow = Wfc + ch * 32;
        int p = 0;
        #pragma unroll
        for (int i = 0; i < 32; ++i) p += __popc(cur[r][i] ^ wrow[i]);
        out[(size_t)(row0 + r) * 10 + ch] = (float)(1024 - 2 * p) * sfc + bfc[ch];
    }
}

extern "C" void kernel_launch(void* const* d_in, const int* in_sizes, int n_in,
                              void* d_out, int out_size, void* d_ws, size_t ws_size,
                              hipStream_t stream) {
    const float* x   = (const float*)d_in[0];
    const float* w1  = (const float*)d_in[1];
    const float* b1  = (const float*)d_in[2];
    const float* g1  = (const float*)d_in[3];
    const float* be1 = (const float*)d_in[4];
    const float* m1  = (const float*)d_in[5];
    const float* v1  = (const float*)d_in[6];
    const float* w2  = (const float*)d_in[7];
    const float* b2  = (const float*)d_in[8];
    const float* g2  = (const float*)d_in[9];
    const float* be2 = (const float*)d_in[10];
    const float* m2  = (const float*)d_in[11];
    const float* v2  = (const float*)d_in[12];
    const float* w3  = (const float*)d_in[13];
    const float* b3  = (const float*)d_in[14];
    const float* g3  = (const float*)d_in[15];
    const float* be3 = (const float*)d_in[16];
    const float* m3  = (const float*)d_in[17];
    const float* v3  = (const float*)d_in[18];
    const float* wfc = (const float*)d_in[19];
    const float* bfc = (const float*)d_in[20];
    uint32_t* ws = (uint32_t*)d_ws;
    float* out = (float*)d_out;

    const bool split = (ws_size >= (size_t)WS_NEED_SPLIT);

    bnn_prep<<<split ? 1409 : 385, 256, 0, stream>>>(
        x,
        w1, b1, g1, be1, m1, v1,
        w2, b2, g2, be2, m2, v2,
        w3, b3, g3, be3, m3, v3,
        wfc, ws);

    if (split) {
        uint32_t* P = ws + OFF_P/4;
        uint32_t* Q = ws + OFF_Q/4;
        bnn_layer<<<512, 1024, 0, stream>>>(P, ws + OFF_W1/4, (const int*)(ws + OFF_T1/4), Q);
        bnn_layer<<<512, 1024, 0, stream>>>(Q, ws + OFF_W2/4, (const int*)(ws + OFF_T2/4), P);
        bnn_layer<<<512, 1024, 0, stream>>>(P, ws + OFF_W3/4, (const int*)(ws + OFF_T3/4), Q);
        bnn_fc<<<128, 64, 0, stream>>>(Q, ws, bfc, out);
    } else {
        bnn_fused<<<8192 / RWS, 512, 0, stream>>>(x, ws, bfc, out);
    }
}

// Round 13
// 192.572 us; speedup vs baseline: 1.0284x; 1.0284x over previous
//
#include <hip/hip_runtime.h>
#include <stdint.h>

// Workspace byte offsets
#define OFF_W1  0        // 1024*32 u32 packed sign bits (784 bits + zero pad)
#define OFF_W2  131072
#define OFF_W3  262144
#define OFF_WFC 393216   // 10*32 u32
#define OFF_T1  395264   // 1024 int32 popcount thresholds
#define OFF_T2  399360
#define OFF_T3  403456
#define OFF_SFC 407552   // double: mean|wfc|
#define OFF_P   409600   // 1 MB bit buffer (ping), TRANSPOSED [word][row]
#define OFF_Q   1458176  // 1 MB bit buffer (pong), TRANSPOSED [word][row]
#define WS_NEED_SPLIT 2506752u
#define RWS 8            // rows/block in fallback fused kernel

typedef uint32_t u32x16 __attribute__((ext_vector_type(16)));

// ---------------------------------------------------------------------------
// Prep: one dispatch = W-pack + thresholds + wfc + x-pack(transposed).
//   blocks 0..383   : thread = (layer, channel o, word k); packs 32 weights
//                     into one u32 (bit=1 <=> w>=0, sign(0)=+1); per-channel
//                     mean|w| via half-wave shfl_xor tree. Threshold (double,
//                     exact): dot = K-2p; layer+BN+sign == (p <= Tint[o]).
//   block 384       : wfc pack (320 words) + global mean|wfc| block-reduce.
//   blocks 385..1408: x-pack -> TRANSPOSED bit-plane layout xpT[w*8192 + r]
//                     (bit j of word w = x[r][32w+j] >= 0.5; words 25..31=0).
// ---------------------------------------------------------------------------
__global__ __launch_bounds__(256) void bnn_prep(
    const float* __restrict__ x,
    const float* __restrict__ w1, const float* __restrict__ b1, const float* __restrict__ g1,
    const float* __restrict__ be1, const float* __restrict__ m1, const float* __restrict__ v1,
    const float* __restrict__ w2, const float* __restrict__ b2, const float* __restrict__ g2,
    const float* __restrict__ be2, const float* __restrict__ m2, const float* __restrict__ v2,
    const float* __restrict__ w3, const float* __restrict__ b3, const float* __restrict__ g3,
    const float* __restrict__ be3, const float* __restrict__ m3, const float* __restrict__ v3,
    const float* __restrict__ wfc,
    uint32_t* __restrict__ ws)
{
    const int blk  = blockIdx.x;
    const int t    = threadIdx.x;
    const int lane = t & 63;
    const int wv   = t >> 6;

    if (blk < 384) {
        const int gid = blk * 256 + t;      // 0..98303
        const int l   = gid >> 15;          // layer 0..2 (32768 words each)
        const int rem = gid & 32767;
        const int o   = rem >> 5;           // channel
        const int k   = rem & 31;           // word within channel
        const float *w, *bb, *g, *be, *m, *v;
        int K; uint32_t* Wp; int* T;
        if (l == 0)      { w=w1; bb=b1; g=g1; be=be1; m=m1; v=v1; K=784;  Wp = ws + OFF_W1/4; T = (int*)(ws + OFF_T1/4); }
        else if (l == 1) { w=w2; bb=b2; g=g2; be=be2; m=m2; v=v2; K=1024; Wp = ws + OFF_W2/4; T = (int*)(ws + OFF_T2/4); }
        else             { w=w3; bb=b3; g=g3; be=be3; m=m3; v=v3; K=1024; Wp = ws + OFF_W3/4; T = (int*)(ws + OFF_T3/4); }

        const int base = 32 * k;
        uint32_t bits = 0;
        double s = 0.0;
        if (base < K) {
            const float4* p = (const float4*)(w + (size_t)o * K + base);
            const int n4 = (K - base >= 32) ? 8 : 4;   // K=784, k=24 -> 16 elems
            for (int i = 0; i < n4; ++i) {
                float4 q = p[i];
                bits |= (q.x >= 0.0f) ? (1u << (4*i + 0)) : 0u;
                bits |= (q.y >= 0.0f) ? (1u << (4*i + 1)) : 0u;
                bits |= (q.z >= 0.0f) ? (1u << (4*i + 2)) : 0u;
                bits |= (q.w >= 0.0f) ? (1u << (4*i + 3)) : 0u;
                s += fabs((double)q.x) + fabs((double)q.y)
                   + fabs((double)q.z) + fabs((double)q.w);
            }
        }
        // half-wave (32-lane) xor tree: all lanes of the half get channel sum
        #pragma unroll
        for (int mask = 1; mask <= 16; mask <<= 1)
            s += __shfl_xor(s, mask, 64);
        if (k == 0) {
            double scale = s / (double)K;                        // mean|w| > 0
            double r = (double)g[o] / sqrt((double)v[o] + 1e-5); // > 0
            double tt = (((double)m[o] - (double)bb[o]) * r - (double)be[o]) / (scale * r);
            double C  = ceil(tt);                                // dot >= C
            double Td = floor(((double)K - C) * 0.5);            // p <= Td
            Td = fmax(fmin(Td, 100000.0), -1.0);
            T[o] = (int)Td;
        }
        Wp[(size_t)o * 32 + k] = bits;
    } else if (blk == 384) {
        // wfc: 320 words (10 ch x 32); thread t does word t and (t<64) t+256
        uint32_t* Wp = ws + OFF_WFC/4;
        double s = 0.0;
        {
            const int o = t >> 5, k = t & 31;
            const float4* p = (const float4*)(wfc + o * 1024 + 32 * k);
            uint32_t bits = 0;
            #pragma unroll
            for (int i = 0; i < 8; ++i) {
                float4 q = p[i];
                bits |= (q.x >= 0.0f) ? (1u << (4*i + 0)) : 0u;
                bits |= (q.y >= 0.0f) ? (1u << (4*i + 1)) : 0u;
                bits |= (q.z >= 0.0f) ? (1u << (4*i + 2)) : 0u;
                bits |= (q.w >= 0.0f) ? (1u << (4*i + 3)) : 0u;
                s += fabs((double)q.x) + fabs((double)q.y)
                   + fabs((double)q.z) + fabs((double)q.w);
            }
            Wp[t] = bits;
        }
        if (t < 64) {
            const int t2 = t + 256;
            const int o = t2 >> 5, k = t2 & 31;
            const float4* p = (const float4*)(wfc + o * 1024 + 32 * k);
            uint32_t bits = 0;
            #pragma unroll
            for (int i = 0; i < 8; ++i) {
                float4 q = p[i];
                bits |= (q.x >= 0.0f) ? (1u << (4*i + 0)) : 0u;
                bits |= (q.y >= 0.0f) ? (1u << (4*i + 1)) : 0u;
                bits |= (q.z >= 0.0f) ? (1u << (4*i + 2)) : 0u;
                bits |= (q.w >= 0.0f) ? (1u << (4*i + 3)) : 0u;
                s += fabs((double)q.x) + fabs((double)q.y)
                   + fabs((double)q.z) + fabs((double)q.w);
            }
            Wp[t2] = bits;
        }
        __shared__ double red[4];
        #pragma unroll
        for (int off = 32; off > 0; off >>= 1) s += __shfl_down(s, off, 64);
        if (lane == 0) red[wv] = s;
        __syncthreads();
        if (t == 0)
            *(double*)(ws + OFF_SFC/4) = (red[0] + red[1] + red[2] + red[3]) / 10240.0;
    } else {
        // x-pack (split path): thread = one u32 word, WRITE TRANSPOSED
        const int gid = (blk - 385) * 256 + t;   // 0..262143
        const int r = gid >> 5;
        const int w = gid & 31;
        uint32_t bits = 0;
        if (w < 24) {
            const float4* p = (const float4*)(x + (size_t)r * 784 + 32 * w);
            #pragma unroll
            for (int i = 0; i < 8; ++i) {
                float4 q = p[i];
                bits |= (q.x >= 0.5f) ? (1u << (4*i + 0)) : 0u;
                bits |= (q.y >= 0.5f) ? (1u << (4*i + 1)) : 0u;
                bits |= (q.z >= 0.5f) ? (1u << (4*i + 2)) : 0u;
                bits |= (q.w >= 0.5f) ? (1u << (4*i + 3)) : 0u;
            }
        } else if (w == 24) {
            const float4* p = (const float4*)(x + (size_t)r * 784 + 768);
            #pragma unroll
            for (int i = 0; i < 4; ++i) {
                float4 q = p[i];
                bits |= (q.x >= 0.5f) ? (1u << (4*i + 0)) : 0u;
                bits |= (q.y >= 0.5f) ? (1u << (4*i + 1)) : 0u;
                bits |= (q.z >= 0.5f) ? (1u << (4*i + 2)) : 0u;
                bits |= (q.w >= 0.5f) ? (1u << (4*i + 3)) : 0u;
            }
        }
        (ws + OFF_P/4)[(size_t)w * 8192 + r] = bits;   // bit-plane layout
    }
}

// ---------------------------------------------------------------------------
// Layer kernel, lane = batch row, TRANSPOSED activations actT[w*8192+row].
// R8-R12 lesson: with act[row][word], lane=row made every A access 128B-
// strided (64 cache lines / instr -> ~6.8us/CU/layer of pure address
// processing) and every u16 store a 64-line sub-dword scatter; that geometry
// —not W-path latency— was the ~20us/layer floor (W fixes R10-R12 all noise).
// Now: A = 32 x fully-coalesced global_load_dword (256B/instr); store = 64
// consecutive u16s (stride 4B, 4 lines). W via s_load_dwordx16 channel-pairs
// (scalar pipe). VGPR ~48 < 64-cap at 8 waves/SIMD -> no remat pressure.
// Grid 512 = 128 rg x 4 cg, block 1024 (16 waves, 2 blk/CU).
// Wave = 16 channels: slice = cg*16+wv; u16 halfword (s&1) of u32 word s>>1.
// ---------------------------------------------------------------------------
__global__ __launch_bounds__(1024) void bnn_layer(
    const uint32_t* __restrict__ actInT,
    const uint32_t* __restrict__ W,
    const int* __restrict__ T,
    uint32_t* __restrict__ actOutT)
{
    const int t    = threadIdx.x;
    const int lane = t & 63;
    const int wv   = t >> 6;            // 0..15
    const int rg   = blockIdx.x >> 2;   // 0..127
    const int cg   = blockIdx.x & 3;    // 0..3
    const int row  = rg * 64 + lane;

    uint32_t A[32];
    #pragma unroll
    for (int i = 0; i < 32; ++i)
        A[i] = actInT[(size_t)i * 8192 + row];   // coalesced 256 B / instr

    const int slice = __builtin_amdgcn_readfirstlane(cg * 16 + wv);   // 0..63
    const int* tp = T + slice * 16;     // uniform -> scalar loads

    uint32_t outw = 0;
    #pragma unroll
    for (int c = 0; c < 16; c += 2) {
        const uint32_t* wp = W + (((size_t)slice * 16 + c) << 5);
        u32x16 w0lo, w0hi, w1lo, w1hi;
        asm volatile("s_load_dwordx16 %0, %4, 0x0\n\t"
                     "s_load_dwordx16 %1, %4, 0x40\n\t"
                     "s_load_dwordx16 %2, %4, 0x80\n\t"
                     "s_load_dwordx16 %3, %4, 0xc0\n\t"
                     "s_waitcnt lgkmcnt(0)"
                     : "=s"(w0lo), "=s"(w0hi), "=s"(w1lo), "=s"(w1hi)
                     : "s"(wp));
        int pa = 0, pb = 0, pc = 0, pd = 0;   // 4 chains (2 per channel)
        #pragma unroll
        for (int i = 0; i < 16; ++i) {
            pa += __popc(A[i]      ^ w0lo[i]);
            pb += __popc(A[i + 16] ^ w0hi[i]);
            pc += __popc(A[i]      ^ w1lo[i]);
            pd += __popc(A[i + 16] ^ w1hi[i]);
        }
        outw |= ((pa + pb) <= tp[c])     ? (1u << c)       : 0u;
        outw |= ((pc + pd) <= tp[c + 1]) ? (1u << (c + 1)) : 0u;
    }
    // u16 halfword (slice&1) of u32 word (slice>>1), transposed layout
    ((uint16_t*)actOutT)[(size_t)(slice >> 1) * 16384 + 2 * row + (slice & 1)]
        = (uint16_t)outw;
}

// FC: lane = row; transposed act3 reads. out = (1024-2p)*sfc + bfc[c].
__global__ __launch_bounds__(64) void bnn_fc(
    const uint32_t* __restrict__ act3T,
    const uint32_t* __restrict__ ws,
    const float* __restrict__ bfc,
    float* __restrict__ out)
{
    const int lane = threadIdx.x;
    const int row  = blockIdx.x * 64 + lane;

    uint32_t A[32];
    #pragma unroll
    for (int i = 0; i < 32; ++i)
        A[i] = act3T[(size_t)i * 8192 + row];    // coalesced

    const float sfc = (float)(*(const double*)(ws + OFF_SFC/4));
    const uint32_t* Wfc = ws + OFF_WFC/4;
    #pragma unroll
    for (int ch = 0; ch < 10; ++ch) {
        const uint32_t* wp = Wfc + ch * 32;
        int p = 0;
        #pragma unroll
        for (int i = 0; i < 32; ++i) p += __popc(A[i] ^ wp[i]);
        out[(size_t)row * 10 + ch] = (float)(1024 - 2 * p) * sfc + bfc[ch];
    }
}

// ---------------------------------------------------------------------------
// FALLBACK fused kernel (R4, 89.5us; ws need 408 KB) — used if ws too small.
// Row-major x, independent of the transposed buffers.
// ---------------------------------------------------------------------------
__global__ __launch_bounds__(512, 4) void bnn_fused(
    const float* __restrict__ x,
    const uint32_t* __restrict__ ws,
    const float* __restrict__ bfc,
    float* __restrict__ out)
{
    __shared__ alignas(16) uint32_t bufA[RWS][32];
    __shared__ alignas(16) uint32_t bufB[RWS][32];
    const int t    = threadIdx.x;
    const int lane = t & 63;
    const int wv   = t >> 6;
    const int row0 = blockIdx.x * RWS;

    {
        const float* xr = x + (size_t)(row0 + wv) * 784;
        #pragma unroll
        for (int k = 0; k < 13; ++k) {
            const int idx = k * 64 + lane;
            const bool bit = (idx < 784) && (xr[idx] >= 0.5f);
            unsigned long long m = __ballot(bit);
            if (lane == 0) *(uint64_t*)(&bufA[wv][2 * k]) = m;
        }
        if (lane == 0) {
            *(uint64_t*)(&bufA[wv][26]) = 0ull;
            *(uint64_t*)(&bufA[wv][28]) = 0ull;
            *(uint64_t*)(&bufA[wv][30]) = 0ull;
        }
    }
    __syncthreads();

    const uint32_t* Wbase[3] = { ws + OFF_W1/4, ws + OFF_W2/4, ws + OFF_W3/4 };
    const int*      Tbase[3] = { (const int*)(ws + OFF_T1/4), (const int*)(ws + OFF_T2/4), (const int*)(ws + OFF_T3/4) };

    uint32_t (*cur)[32] = bufA;
    uint32_t (*nxt)[32] = bufB;
    const int c0 = t, c1 = t + 512;

    for (int l = 0; l < 3; ++l) {
        uint32_t W0[32], W1[32];
        {
            const uint4* p0 = (const uint4*)(Wbase[l] + (size_t)c0 * 32);
            const uint4* p1 = (const uint4*)(Wbase[l] + (size_t)c1 * 32);
            #pragma unroll
            for (int i = 0; i < 8; ++i) { ((uint4*)W0)[i] = p0[i]; ((uint4*)W1)[i] = p1[i]; }
        }
        const int T0 = Tbase[l][c0];
        const int T1 = Tbase[l][c1];

        for (int r = 0; r < RWS; ++r) {
            uint32_t A[32];
            #pragma unroll
            for (int i = 0; i < 8; ++i) ((uint4*)A)[i] = ((const uint4*)cur[r])[i];
            int pa = 0, pb = 0, pc = 0, pd = 0;
            #pragma unroll
            for (int i = 0; i < 16; ++i) {
                pa += __popc(A[i]      ^ W0[i]);
                pb += __popc(A[i + 16] ^ W0[i + 16]);
                pc += __popc(A[i]      ^ W1[i]);
                pd += __popc(A[i + 16] ^ W1[i + 16]);
            }
            unsigned long long m0 = __ballot((pa + pb) <= T0);
            unsigned long long m1 = __ballot((pc + pd) <= T1);
            if (lane == 0) {
                *(uint64_t*)(&nxt[r][2 * wv])      = m0;
                *(uint64_t*)(&nxt[r][16 + 2 * wv]) = m1;
            }
        }
        __syncthreads();
        uint32_t (*tmp)[32] = cur; cur = nxt; nxt = tmp;
    }

    if (t < RWS * 10) {
        const float sfc = (float)(*(const double*)(ws + OFF_SFC/4));
        const uint32_t* Wfc = ws + OFF_WFC/4;
        const int r = t / 10, ch = t % 10;
        const uint32_t* wrow = Wfc + ch * 32;
        int p = 0;
        #pragma unroll
        for (int i = 0; i < 32; ++i) p += __popc(cur[r][i] ^ wrow[i]);
        out[(size_t)(row0 + r) * 10 + ch] = (float)(1024 - 2 * p) * sfc + bfc[ch];
    }
}

extern "C" void kernel_launch(void* const* d_in, const int* in_sizes, int n_in,
                              void* d_out, int out_size, void* d_ws, size_t ws_size,
                              hipStream_t stream) {
    const float* x   = (const float*)d_in[0];
    const float* w1  = (const float*)d_in[1];
    const float* b1  = (const float*)d_in[2];
    const float* g1  = (const float*)d_in[3];
    const float* be1 = (const float*)d_in[4];
    const float* m1  = (const float*)d_in[5];
    const float* v1  = (const float*)d_in[6];
    const float* w2  = (const float*)d_in[7];
    const float* b2  = (const float*)d_in[8];
    const float* g2  = (const float*)d_in[9];
    const float* be2 = (const float*)d_in[10];
    const float* m2  = (const float*)d_in[11];
    const float* v2  = (const float*)d_in[12];
    const float* w3  = (const float*)d_in[13];
    const float* b3  = (const float*)d_in[14];
    const float* g3  = (const float*)d_in[15];
    const float* be3 = (const float*)d_in[16];
    const float* m3  = (const float*)d_in[17];
    const float* v3  = (const float*)d_in[18];
    const float* wfc = (const float*)d_in[19];
    const float* bfc = (const float*)d_in[20];
    uint32_t* ws = (uint32_t*)d_ws;
    float* out = (float*)d_out;

    const bool split = (ws_size >= (size_t)WS_NEED_SPLIT);

    bnn_prep<<<split ? 1409 : 385, 256, 0, stream>>>(
        x,
        w1, b1, g1, be1, m1, v1,
        w2, b2, g2, be2, m2, v2,
        w3, b3, g3, be3, m3, v3,
        wfc, ws);

    if (split) {
        uint32_t* P = ws + OFF_P/4;
        uint32_t* Q = ws + OFF_Q/4;
        bnn_layer<<<512, 1024, 0, stream>>>(P, ws + OFF_W1/4, (const int*)(ws + OFF_T1/4), Q);
        bnn_layer<<<512, 1024, 0, stream>>>(Q, ws + OFF_W2/4, (const int*)(ws + OFF_T2/4), P);
        bnn_layer<<<512, 1024, 0, stream>>>(P, ws + OFF_W3/4, (const int*)(ws + OFF_T3/4), Q);
        bnn_fc<<<128, 64, 0, stream>>>(Q, ws, bfc, out);
    } else {
        bnn_fused<<<8192 / RWS, 512, 0, stream>>>(x, ws, bfc, out);
    }
}